// Round 2
// baseline (74.319 us; speedup 1.0000x reference)
//
#include <hip/hip_runtime.h>

#define NNODES 4096
#define INF_   256
#define HEADS  8
#define FDIM   64
#define HO     512            // HEADS*FDIM
#define NEDGES 131072
#define NEG_SLOPE 0.2f
#define MWORDS 128            // 4096 bits / 32 per row

// ---------------- zero adjacency bitmask ----------------
__global__ __launch_bounds__(256) void zero_mask_kernel(unsigned int* __restrict__ mask) {
    int i = blockIdx.x * 256 + threadIdx.x;
    if (i < NNODES * MWORDS) mask[i] = 0u;
}

// ---------------- scatter edges into bitmask (dedups duplicates) + self loops ----------------
__global__ __launch_bounds__(256) void build_adj_kernel(const int* __restrict__ ei,
                                                        unsigned int* __restrict__ mask) {
    int e = blockIdx.x * 256 + threadIdx.x;
    if (e < NEDGES) {
        int src = ei[e];
        int dst = ei[NEDGES + e];
        atomicOr(&mask[src * MWORDS + (dst >> 5)], 1u << (dst & 31));
    }
    if (e < NNODES) {  // self loop (adj + eye)
        atomicOr(&mask[e * MWORDS + (e >> 5)], 1u << (e & 31));
    }
}

// ---------------- f32 GEMM: h = x @ W   (4096x256 * 256x512) ----------------
// 64x64 tile per 256-thread block, 4x4 per thread, BK=32
__global__ __launch_bounds__(256) void gemm_xw(const float* __restrict__ x,
                                               const float* __restrict__ W,
                                               float* __restrict__ hout) {
    __shared__ float As[32][68];  // As[k][m]  (transposed x tile)
    __shared__ float Bs[32][68];  // Bs[k][n]
    int bi = blockIdx.x, bj = blockIdx.y;
    int t  = threadIdx.x;
    int tm = t >> 4, tn = t & 15;
    float acc[4][4] = {};
    for (int k0 = 0; k0 < INF_; k0 += 32) {
        #pragma unroll
        for (int r = 0; r < 2; ++r) {
            int idx = (t + r * 256) * 4;  // 0..2044
            // A tile: 64 rows x 32 cols
            int arow = idx >> 5, acol = idx & 31;
            float4 va = *reinterpret_cast<const float4*>(&x[(size_t)(bi * 64 + arow) * INF_ + k0 + acol]);
            As[acol + 0][arow] = va.x;
            As[acol + 1][arow] = va.y;
            As[acol + 2][arow] = va.z;
            As[acol + 3][arow] = va.w;
            // B tile: 32 rows x 64 cols
            int brow = idx >> 6, bcol = idx & 63;
            float4 vb = *reinterpret_cast<const float4*>(&W[(size_t)(k0 + brow) * HO + bj * 64 + bcol]);
            *reinterpret_cast<float4*>(&Bs[brow][bcol]) = vb;
        }
        __syncthreads();
        #pragma unroll
        for (int k = 0; k < 32; ++k) {
            float4 av = *reinterpret_cast<const float4*>(&As[k][tm * 4]);
            float4 bv = *reinterpret_cast<const float4*>(&Bs[k][tn * 4]);
            float am[4] = {av.x, av.y, av.z, av.w};
            float bm[4] = {bv.x, bv.y, bv.z, bv.w};
            #pragma unroll
            for (int i = 0; i < 4; ++i)
                #pragma unroll
                for (int j = 0; j < 4; ++j)
                    acc[i][j] += am[i] * bm[j];
        }
        __syncthreads();
    }
    #pragma unroll
    for (int i = 0; i < 4; ++i) {
        float4 v = {acc[i][0], acc[i][1], acc[i][2], acc[i][3]};
        *reinterpret_cast<float4*>(&hout[(size_t)(bi * 64 + tm * 4 + i) * HO + bj * 64 + tn * 4]) = v;
    }
}

// ---------------- e_src / e_dst: per (node, head) dot over F=64 ----------------
__global__ __launch_bounds__(256) void compute_ee(const float* __restrict__ h,
                                                  const float* __restrict__ a,
                                                  float* __restrict__ es,
                                                  float* __restrict__ ed) {
    int wave = threadIdx.x >> 6;
    int lane = threadIdx.x & 63;
    int n = blockIdx.x * 4 + wave;
    const float* hn = h + (size_t)n * HO;
    #pragma unroll
    for (int hh = 0; hh < HEADS; ++hh) {
        float v  = hn[hh * FDIM + lane];
        float ps = v * a[hh * 2 * FDIM + lane];
        float pd = v * a[hh * 2 * FDIM + FDIM + lane];
        #pragma unroll
        for (int off = 32; off; off >>= 1) {
            ps += __shfl_down(ps, off);
            pd += __shfl_down(pd, off);
        }
        if (lane == 0) {
            es[n * HEADS + hh] = ps;
            ed[n * HEADS + hh] = pd;
        }
    }
}

// ---------------- per-row masked softmax + aggregate ----------------
// one 256-thread block per destination row i
__global__ __launch_bounds__(256) void gat_aggregate(const float* __restrict__ h,
                                                     const float* __restrict__ es,
                                                     const float* __restrict__ ed,
                                                     const unsigned int* __restrict__ mask,
                                                     float* __restrict__ out) {
    int i = blockIdx.x;
    int t = threadIdx.x;
    __shared__ unsigned short list[NNODES];
    __shared__ int cnt;
    __shared__ float partial[256];
    __shared__ float mh[HEADS];
    if (t == 0) cnt = 0;
    __syncthreads();
    // Phase A: scan the 128-word bitmask row, build neighbor list
    const unsigned int* row = mask + (size_t)i * MWORDS;
    for (int w = t; w < MWORDS; w += 256) {
        unsigned int bits = row[w];
        while (bits) {
            int b = __ffs(bits) - 1;
            bits &= bits - 1;
            int pos = atomicAdd(&cnt, 1);
            list[pos] = (unsigned short)(w * 32 + b);
        }
    }
    __syncthreads();
    int deg = cnt;
    // Phase B: per-head max of leaky_relu(es_i + ed_j) over neighbors
    {
        int hh = t & 7;
        int lane = t >> 3;  // 32 threads per head
        float m = -1e30f;
        float es_h = es[i * HEADS + hh];
        for (int jj = lane; jj < deg; jj += 32) {
            int j = list[jj];
            float s = es_h + ed[j * HEADS + hh];
            s = s > 0.f ? s : NEG_SLOPE * s;
            m = fmaxf(m, s);
        }
        partial[t] = m;
    }
    __syncthreads();
    if (t < HEADS) {
        float mm = partial[t];
        #pragma unroll
        for (int q = 1; q < 32; ++q) mm = fmaxf(mm, partial[t + q * 8]);
        mh[t] = mm;
    }
    __syncthreads();
    // Phase C: weighted accumulation. thread t owns feature f = t&63 of heads h0 and h0+4
    int f  = t & 63;
    int h0 = t >> 6;      // 0..3
    int h1 = h0 + 4;
    float es0 = es[i * HEADS + h0], es1 = es[i * HEADS + h1];
    float m0 = mh[h0], m1 = mh[h1];
    float acc0 = 0.f, acc1 = 0.f, d0 = 0.f, d1 = 0.f;
    for (int jj = 0; jj < deg; ++jj) {
        int j = list[jj];
        const float* hj = h + (size_t)j * HO;
        float e0 = ed[j * HEADS + h0], e1 = ed[j * HEADS + h1];
        float s0 = es0 + e0; s0 = s0 > 0.f ? s0 : NEG_SLOPE * s0;
        float s1 = es1 + e1; s1 = s1 > 0.f ? s1 : NEG_SLOPE * s1;
        float w0 = __expf(s0 - m0);
        float w1 = __expf(s1 - m1);
        acc0 += w0 * hj[h0 * FDIM + f];
        acc1 += w1 * hj[h1 * FDIM + f];
        d0 += w0;
        d1 += w1;
    }
    out[(size_t)i * HO + h0 * FDIM + f] = acc0 / d0;
    out[(size_t)i * HO + h1 * FDIM + f] = acc1 / d1;
}

extern "C" void kernel_launch(void* const* d_in, const int* in_sizes, int n_in,
                              void* d_out, int out_size, void* d_ws, size_t ws_size,
                              hipStream_t stream) {
    const float* x  = (const float*)d_in[0];
    const int*   ei = (const int*)d_in[1];
    const float* W  = (const float*)d_in[2];
    const float* a  = (const float*)d_in[3];
    float* out = (float*)d_out;

    char* ws = (char*)d_ws;
    float* h  = (float*)ws;                                    // 4096*512*4 = 8 MB
    float* es = (float*)(ws + (size_t)NNODES * HO * 4);        // 128 KB
    float* ed = es + NNODES * HEADS;                           // 128 KB
    unsigned int* mask = (unsigned int*)(ed + NNODES * HEADS); // 2 MB

    hipLaunchKernelGGL(zero_mask_kernel,
                       dim3((NNODES * MWORDS + 255) / 256), dim3(256), 0, stream, mask);
    hipLaunchKernelGGL(build_adj_kernel,
                       dim3((NEDGES + 255) / 256), dim3(256), 0, stream, ei, mask);
    hipLaunchKernelGGL(gemm_xw, dim3(64, 8), dim3(256), 0, stream, x, W, h);
    hipLaunchKernelGGL(compute_ee, dim3(NNODES / 4), dim3(256), 0, stream, h, a, es, ed);
    hipLaunchKernelGGL(gat_aggregate, dim3(NNODES), dim3(256), 0, stream, h, es, ed, mask, out);
}

// Round 3
// 57.188 us; speedup vs baseline: 1.2995x; 1.2995x over previous
//
#include <hip/hip_runtime.h>

#define NNODES 4096
#define INF_   256
#define HEADS  8
#define FDIM   64
#define HO     512            // HEADS*FDIM
#define NEDGES 131072
#define NEG_SLOPE 0.2f
#define MWORDS 128            // 4096 bits / 32 per row
#define GEMM_BLOCKS 512       // 64 x 8 tile grid
#define ADJ_BLOCKS  512       // 131072 / 256

// ============ fused: GEMM h=x@W (+ee epilogue)  ||  adjacency scatter ============
// blocks [0,512): gemm 64x64 tile, bi=b>>3, bj=b&7 (bj == head index)
// blocks [512,1024): edge scatter into bitmask
__global__ __launch_bounds__(256) void fused_gemm_adj(const float* __restrict__ x,
                                                      const float* __restrict__ W,
                                                      const float* __restrict__ a,
                                                      const int* __restrict__ ei,
                                                      unsigned int* __restrict__ mask,
                                                      float* __restrict__ hout,
                                                      float* __restrict__ es,
                                                      float* __restrict__ ed) {
    __shared__ float As[32][68];  // As[k][m]
    __shared__ float Bs[32][68];  // Bs[k][n]
    int b = blockIdx.x;
    int t = threadIdx.x;

    if (b >= GEMM_BLOCKS) {
        // ---- adjacency path (dedups duplicate edges via bitmask OR) ----
        int e = (b - GEMM_BLOCKS) * 256 + t;
        if (e < NEDGES) {
            int src = ei[e];
            int dst = ei[NEDGES + e];
            atomicOr(&mask[src * MWORDS + (dst >> 5)], 1u << (dst & 31));
        }
        if (e < NNODES) {  // self loop (adj + eye)
            atomicOr(&mask[e * MWORDS + (e >> 5)], 1u << (e & 31));
        }
        return;
    }

    // ---- GEMM path ----
    int bi = b >> 3, bj = b & 7;
    int tm = t >> 4, tn = t & 15;
    float acc[4][4] = {};
    for (int k0 = 0; k0 < INF_; k0 += 32) {
        #pragma unroll
        for (int r = 0; r < 2; ++r) {
            int idx = (t + r * 256) * 4;
            int arow = idx >> 5, acol = idx & 31;
            float4 va = *reinterpret_cast<const float4*>(&x[(size_t)(bi * 64 + arow) * INF_ + k0 + acol]);
            As[acol + 0][arow] = va.x;
            As[acol + 1][arow] = va.y;
            As[acol + 2][arow] = va.z;
            As[acol + 3][arow] = va.w;
            int brow = idx >> 6, bcol = idx & 63;
            float4 vb = *reinterpret_cast<const float4*>(&W[(size_t)(k0 + brow) * HO + bj * 64 + bcol]);
            *reinterpret_cast<float4*>(&Bs[brow][bcol]) = vb;
        }
        __syncthreads();
        #pragma unroll
        for (int k = 0; k < 32; ++k) {
            float4 av = *reinterpret_cast<const float4*>(&As[k][tm * 4]);
            float4 bv = *reinterpret_cast<const float4*>(&Bs[k][tn * 4]);
            float am[4] = {av.x, av.y, av.z, av.w};
            float bm[4] = {bv.x, bv.y, bv.z, bv.w};
            #pragma unroll
            for (int i = 0; i < 4; ++i)
                #pragma unroll
                for (int j = 0; j < 4; ++j)
                    acc[i][j] += am[i] * bm[j];
        }
        __syncthreads();
    }
    #pragma unroll
    for (int i = 0; i < 4; ++i) {
        float4 v = {acc[i][0], acc[i][1], acc[i][2], acc[i][3]};
        *reinterpret_cast<float4*>(&hout[(size_t)(bi * 64 + tm * 4 + i) * HO + bj * 64 + tn * 4]) = v;
    }
    // ---- ee epilogue: es/ed for the 64 rows of this tile (head bj) ----
    // e_src[n,bj] = sum_f h[n,bj*64+f]*a[bj,f];  e_dst with a[bj,64+f]
    const float* ah = a + bj * 2 * FDIM;
    float ps[4], pd[4];
    #pragma unroll
    for (int i = 0; i < 4; ++i) { ps[i] = 0.f; pd[i] = 0.f; }
    #pragma unroll
    for (int j = 0; j < 4; ++j) {
        float asv = ah[tn * 4 + j];
        float adv = ah[FDIM + tn * 4 + j];
        #pragma unroll
        for (int i = 0; i < 4; ++i) {
            ps[i] += acc[i][j] * asv;
            pd[i] += acc[i][j] * adv;
        }
    }
    #pragma unroll
    for (int i = 0; i < 4; ++i) {
        #pragma unroll
        for (int off = 8; off; off >>= 1) {
            ps[i] += __shfl_down(ps[i], off, 16);
            pd[i] += __shfl_down(pd[i], off, 16);
        }
        if (tn == 0) {
            int r = bi * 64 + tm * 4 + i;
            es[r * HEADS + bj] = ps[i];
            ed[r * HEADS + bj] = pd[i];
        }
    }
}

// ============ per-row softmax + aggregation, one block per destination row ============
// Deterministic scan-based neighbor list; no max pass (|e| small -> expf safe);
// 4-way wave split over neighbors, register accumulators, LDS tree reduce.
__global__ __launch_bounds__(256) void gat_aggregate(const float* __restrict__ h,
                                                     const float* __restrict__ es,
                                                     const float* __restrict__ ed,
                                                     const unsigned int* __restrict__ mask,
                                                     float* __restrict__ out) {
    int i = blockIdx.x;
    int t = threadIdx.x;
    int wave = t >> 6, lane = t & 63;
    __shared__ unsigned short list[NNODES];   // 8 KB (max degree)
    __shared__ float red[4][HO];              // 8 KB per-wave feature partials
    __shared__ float redd[4][HEADS];          // per-wave denominator partials
    __shared__ float s_wtot;
    __shared__ int   s_w0, s_deg;

    // ---- deterministic list build: word-per-thread popcount + wave prefix scan ----
    unsigned int bits = 0;
    int cnt = 0, incl = 0;
    if (t < 128) {
        bits = mask[(size_t)i * MWORDS + t];
        cnt = __popc(bits);
        incl = cnt;
        #pragma unroll
        for (int off = 1; off < 64; off <<= 1) {
            int v = __shfl_up(incl, off);
            if (lane >= off) incl += v;
        }
    }
    if (t == 63) s_w0 = incl;
    __syncthreads();
    if (t >= 64 && t < 128) incl += s_w0;
    if (t == 127) s_deg = incl;
    if (t < 128) {
        int pos = incl - cnt;
        int base = t * 32;
        while (bits) {
            int bbit = __ffs(bits) - 1;
            bits &= bits - 1;
            list[pos++] = (unsigned short)(base + bbit);
        }
    }
    __syncthreads();
    int deg = s_deg;

    // ---- accumulate: wave w takes neighbors w, w+4, ...; lane owns features lane*8..+7 ----
    int hh = lane >> 3;         // head of this lane's features
    int f0 = lane * 8;
    float es_h = es[i * HEADS + hh];
    float acc[8] = {0.f, 0.f, 0.f, 0.f, 0.f, 0.f, 0.f, 0.f};
    float den = 0.f;
    for (int jj = wave; jj < deg; jj += 4) {
        int j = list[jj];
        float s = es_h + ed[j * HEADS + hh];
        s = s > 0.f ? s : NEG_SLOPE * s;
        float w = __expf(s);
        const float4* hp = reinterpret_cast<const float4*>(h + (size_t)j * HO + f0);
        float4 v0 = hp[0], v1 = hp[1];
        acc[0] += w * v0.x; acc[1] += w * v0.y; acc[2] += w * v0.z; acc[3] += w * v0.w;
        acc[4] += w * v1.x; acc[5] += w * v1.y; acc[6] += w * v1.z; acc[7] += w * v1.w;
        den += w;
    }
    float4 a0 = {acc[0], acc[1], acc[2], acc[3]};
    float4 a1 = {acc[4], acc[5], acc[6], acc[7]};
    *reinterpret_cast<float4*>(&red[wave][f0]) = a0;
    *reinterpret_cast<float4*>(&red[wave][f0 + 4]) = a1;
    if ((lane & 7) == 0) redd[wave][hh] = den;
    __syncthreads();

    // ---- combine 4 wave-partials, normalize, store ----
    #pragma unroll
    for (int ff = t; ff < HO; ff += 256) {
        float sum = red[0][ff] + red[1][ff] + red[2][ff] + red[3][ff];
        int hd = ff >> 6;
        float d = redd[0][hd] + redd[1][hd] + redd[2][hd] + redd[3][hd];
        out[(size_t)i * HO + ff] = sum / d;
    }
}

extern "C" void kernel_launch(void* const* d_in, const int* in_sizes, int n_in,
                              void* d_out, int out_size, void* d_ws, size_t ws_size,
                              hipStream_t stream) {
    const float* x  = (const float*)d_in[0];
    const int*   ei = (const int*)d_in[1];
    const float* W  = (const float*)d_in[2];
    const float* a  = (const float*)d_in[3];
    float* out = (float*)d_out;

    char* ws = (char*)d_ws;
    float* h  = (float*)ws;                                    // 8 MB
    float* es = (float*)(ws + (size_t)NNODES * HO * 4);        // 128 KB
    float* ed = es + NNODES * HEADS;                           // 128 KB
    unsigned int* mask = (unsigned int*)(ed + NNODES * HEADS); // 2 MB

    hipMemsetAsync(mask, 0, (size_t)NNODES * MWORDS * 4, stream);
    hipLaunchKernelGGL(fused_gemm_adj, dim3(GEMM_BLOCKS + ADJ_BLOCKS), dim3(256), 0, stream,
                       x, W, a, ei, mask, h, es, ed);
    hipLaunchKernelGGL(gat_aggregate, dim3(NNODES), dim3(256), 0, stream, h, es, ed, mask, out);
}

// Round 4
// 49.520 us; speedup vs baseline: 1.5008x; 1.1549x over previous
//
#include <hip/hip_runtime.h>

#define NNODES 4096
#define INF_   256
#define HEADS  8
#define FDIM   64
#define HO     512            // HEADS*FDIM
#define NEDGES 131072
#define NEG_SLOPE 0.2f
#define MWORDS 128            // 4096 bits / 32 per row
#define GEMM_BLOCKS 512       // 64 x 8 tile grid
#define ADJ_BLOCKS  512       // 131072 / 256

typedef unsigned short ushort_t;

__device__ __forceinline__ float bf16_to_f32(ushort_t u) {
    union { unsigned int i; float f; } c;
    c.i = ((unsigned int)u) << 16;
    return c.f;
}
__device__ __forceinline__ ushort_t f32_to_bf16(float f) {
    union { float f; unsigned int i; } c;
    c.f = f;
    unsigned int r = c.i + 0x7FFF + ((c.i >> 16) & 1);  // round-to-nearest-even
    return (ushort_t)(r >> 16);
}

// ---------------- zero adjacency bitmask (graph-captured memset runs at 48 GB/s — do it ourselves) ----
__global__ __launch_bounds__(256) void zero_mask_kernel(unsigned int* __restrict__ mask) {
    int i = blockIdx.x * 256 + threadIdx.x;
    mask[i] = 0u;   // grid sized exactly NNODES*MWORDS/256
}

// ============ fused: GEMM h=x@W (+ee epilogue)  ||  adjacency scatter ============
__global__ __launch_bounds__(256) void fused_gemm_adj(const float* __restrict__ x,
                                                      const float* __restrict__ W,
                                                      const float* __restrict__ a,
                                                      const int* __restrict__ ei,
                                                      unsigned int* __restrict__ mask,
                                                      ushort_t* __restrict__ hout,
                                                      float* __restrict__ es,
                                                      float* __restrict__ ed) {
    __shared__ float As[32][68];  // As[k][m]
    __shared__ float Bs[32][68];  // Bs[k][n]
    int b = blockIdx.x;
    int t = threadIdx.x;

    if (b >= GEMM_BLOCKS) {
        // ---- adjacency path (dedups duplicate edges via bitmask OR) ----
        int e = (b - GEMM_BLOCKS) * 256 + t;
        if (e < NEDGES) {
            int src = ei[e];
            int dst = ei[NEDGES + e];
            atomicOr(&mask[src * MWORDS + (dst >> 5)], 1u << (dst & 31));
        }
        if (e < NNODES) {  // self loop (adj + eye)
            atomicOr(&mask[e * MWORDS + (e >> 5)], 1u << (e & 31));
        }
        return;
    }

    // ---- GEMM path: 64x64 tile, bi=b>>3, bj=b&7 (bj == head index) ----
    int bi = b >> 3, bj = b & 7;
    int tm = t >> 4, tn = t & 15;
    float acc[4][4] = {};
    for (int k0 = 0; k0 < INF_; k0 += 32) {
        #pragma unroll
        for (int r = 0; r < 2; ++r) {
            int idx = (t + r * 256) * 4;
            int arow = idx >> 5, acol = idx & 31;
            float4 va = *reinterpret_cast<const float4*>(&x[(size_t)(bi * 64 + arow) * INF_ + k0 + acol]);
            As[acol + 0][arow] = va.x;
            As[acol + 1][arow] = va.y;
            As[acol + 2][arow] = va.z;
            As[acol + 3][arow] = va.w;
            int brow = idx >> 6, bcol = idx & 63;
            float4 vb = *reinterpret_cast<const float4*>(&W[(size_t)(k0 + brow) * HO + bj * 64 + bcol]);
            *reinterpret_cast<float4*>(&Bs[brow][bcol]) = vb;
        }
        __syncthreads();
        #pragma unroll
        for (int k = 0; k < 32; ++k) {
            float4 av = *reinterpret_cast<const float4*>(&As[k][tm * 4]);
            float4 bv = *reinterpret_cast<const float4*>(&Bs[k][tn * 4]);
            float am[4] = {av.x, av.y, av.z, av.w};
            float bm[4] = {bv.x, bv.y, bv.z, bv.w};
            #pragma unroll
            for (int i = 0; i < 4; ++i)
                #pragma unroll
                for (int j = 0; j < 4; ++j)
                    acc[i][j] += am[i] * bm[j];
        }
        __syncthreads();
    }
    // ---- h store as bf16 (halves aggregate gather traffic) ----
    #pragma unroll
    for (int i = 0; i < 4; ++i) {
        unsigned int w0 = (unsigned int)f32_to_bf16(acc[i][0]) |
                          ((unsigned int)f32_to_bf16(acc[i][1]) << 16);
        unsigned int w1 = (unsigned int)f32_to_bf16(acc[i][2]) |
                          ((unsigned int)f32_to_bf16(acc[i][3]) << 16);
        uint2 pk = make_uint2(w0, w1);
        *reinterpret_cast<uint2*>(&hout[(size_t)(bi * 64 + tm * 4 + i) * HO + bj * 64 + tn * 4]) = pk;
    }
    // ---- ee epilogue: es/ed for the 64 rows of this tile (head bj), from f32 acc ----
    const float* ah = a + bj * 2 * FDIM;
    float ps[4], pd[4];
    #pragma unroll
    for (int i = 0; i < 4; ++i) { ps[i] = 0.f; pd[i] = 0.f; }
    #pragma unroll
    for (int j = 0; j < 4; ++j) {
        float asv = ah[tn * 4 + j];
        float adv = ah[FDIM + tn * 4 + j];
        #pragma unroll
        for (int i = 0; i < 4; ++i) {
            ps[i] += acc[i][j] * asv;
            pd[i] += acc[i][j] * adv;
        }
    }
    #pragma unroll
    for (int i = 0; i < 4; ++i) {
        #pragma unroll
        for (int off = 8; off; off >>= 1) {
            ps[i] += __shfl_down(ps[i], off, 16);
            pd[i] += __shfl_down(pd[i], off, 16);
        }
        if (tn == 0) {
            int r = bi * 64 + tm * 4 + i;
            es[r * HEADS + bj] = ps[i];
            ed[r * HEADS + bj] = pd[i];
        }
    }
}

// ============ per-row softmax + aggregation, one block per destination row ============
__global__ __launch_bounds__(256) void gat_aggregate(const ushort_t* __restrict__ h,
                                                     const float* __restrict__ es,
                                                     const float* __restrict__ ed,
                                                     const unsigned int* __restrict__ mask,
                                                     float* __restrict__ out) {
    int i = blockIdx.x;
    int t = threadIdx.x;
    int wave = t >> 6, lane = t & 63;
    __shared__ unsigned short list[NNODES];   // 8 KB (max degree)
    __shared__ float red[4][HO];              // 8 KB per-wave feature partials
    __shared__ float redd[4][HEADS];
    __shared__ int   s_w0, s_deg;

    // ---- deterministic list build: popcount + wave prefix scan ----
    unsigned int bits = 0;
    int cnt = 0, incl = 0;
    if (t < 128) {
        bits = mask[(size_t)i * MWORDS + t];
        cnt = __popc(bits);
        incl = cnt;
        #pragma unroll
        for (int off = 1; off < 64; off <<= 1) {
            int v = __shfl_up(incl, off);
            if (lane >= off) incl += v;
        }
    }
    if (t == 63) s_w0 = incl;
    __syncthreads();
    if (t >= 64 && t < 128) incl += s_w0;
    if (t == 127) s_deg = incl;
    if (t < 128) {
        int pos = incl - cnt;
        int base = t * 32;
        while (bits) {
            int bbit = __ffs(bits) - 1;
            bits &= bits - 1;
            list[pos++] = (unsigned short)(base + bbit);
        }
    }
    __syncthreads();
    int deg = s_deg;

    // ---- accumulate: wave w takes neighbors w, w+4, ...; lane owns features lane*8..+7 ----
    int hh = lane >> 3;
    int f0 = lane * 8;
    float es_h = es[i * HEADS + hh];
    float acc[8] = {0.f, 0.f, 0.f, 0.f, 0.f, 0.f, 0.f, 0.f};
    float den = 0.f;
    for (int jj = wave; jj < deg; jj += 4) {
        int j = list[jj];
        float s = es_h + ed[j * HEADS + hh];
        s = s > 0.f ? s : NEG_SLOPE * s;
        float w = __expf(s);
        uint4 v = *reinterpret_cast<const uint4*>(h + (size_t)j * HO + f0);  // 8 bf16
        acc[0] += w * bf16_to_f32((ushort_t)(v.x & 0xFFFF));
        acc[1] += w * bf16_to_f32((ushort_t)(v.x >> 16));
        acc[2] += w * bf16_to_f32((ushort_t)(v.y & 0xFFFF));
        acc[3] += w * bf16_to_f32((ushort_t)(v.y >> 16));
        acc[4] += w * bf16_to_f32((ushort_t)(v.z & 0xFFFF));
        acc[5] += w * bf16_to_f32((ushort_t)(v.z >> 16));
        acc[6] += w * bf16_to_f32((ushort_t)(v.w & 0xFFFF));
        acc[7] += w * bf16_to_f32((ushort_t)(v.w >> 16));
        den += w;
    }
    float4 a0 = {acc[0], acc[1], acc[2], acc[3]};
    float4 a1 = {acc[4], acc[5], acc[6], acc[7]};
    *reinterpret_cast<float4*>(&red[wave][f0]) = a0;
    *reinterpret_cast<float4*>(&red[wave][f0 + 4]) = a1;
    if ((lane & 7) == 0) redd[wave][hh] = den;
    __syncthreads();

    #pragma unroll
    for (int ff = t; ff < HO; ff += 256) {
        float sum = red[0][ff] + red[1][ff] + red[2][ff] + red[3][ff];
        int hd = ff >> 6;
        float d = redd[0][hd] + redd[1][hd] + redd[2][hd] + redd[3][hd];
        out[(size_t)i * HO + ff] = sum / d;
    }
}

extern "C" void kernel_launch(void* const* d_in, const int* in_sizes, int n_in,
                              void* d_out, int out_size, void* d_ws, size_t ws_size,
                              hipStream_t stream) {
    const float* x  = (const float*)d_in[0];
    const int*   ei = (const int*)d_in[1];
    const float* W  = (const float*)d_in[2];
    const float* a  = (const float*)d_in[3];
    float* out = (float*)d_out;

    char* ws = (char*)d_ws;
    ushort_t* h = (ushort_t*)ws;                               // 4096*512*2 = 4 MB
    float* es = (float*)(ws + (size_t)NNODES * HO * 2);        // 128 KB
    float* ed = es + NNODES * HEADS;                           // 128 KB
    unsigned int* mask = (unsigned int*)(ed + NNODES * HEADS); // 2 MB

    hipLaunchKernelGGL(zero_mask_kernel,
                       dim3(NNODES * MWORDS / 256), dim3(256), 0, stream, mask);
    hipLaunchKernelGGL(fused_gemm_adj, dim3(GEMM_BLOCKS + ADJ_BLOCKS), dim3(256), 0, stream,
                       x, W, a, ei, mask, h, es, ed);
    hipLaunchKernelGGL(gat_aggregate, dim3(NNODES), dim3(256), 0, stream, h, es, ed, mask, out);
}

// Round 5
// 40.529 us; speedup vs baseline: 1.8337x; 1.2218x over previous
//
#include <hip/hip_runtime.h>

#define NNODES 4096
#define INF_   256
#define HEADS  8
#define FDIM   64
#define HO     512            // HEADS*FDIM
#define NEDGES 131072
#define NEG_SLOPE 0.2f
#define MWORDS 128            // 4096 bits / 32 per row

#define ZB 512                // prep: zero-mask blocks   (512*256 threads * uint4 = 2 MB)
#define XB 1024               // prep: x-convert blocks   (262144 float4)
#define WB 512                // prep: W-transpose blocks (131072 elems)
#define GEMM_BLOCKS 512       // 64 row-tiles x 8 col-tiles(heads)
#define ADJ_BLOCKS  512       // 131072 / 256

typedef unsigned short ushort_t;
typedef short bf16x8 __attribute__((ext_vector_type(8)));   // 8 bf16 in 4 VGPRs
typedef float f32x4  __attribute__((ext_vector_type(4)));

union U16x8 { uint4 u; bf16x8 v; };

__device__ __forceinline__ float bf16_to_f32(ushort_t u) {
    union { unsigned int i; float f; } c;
    c.i = ((unsigned int)u) << 16;
    return c.f;
}
__device__ __forceinline__ ushort_t f32_to_bf16(float f) {
    union { float f; unsigned int i; } c;
    c.f = f;
    unsigned int r = c.i + 0x7FFF + ((c.i >> 16) & 1);  // round-to-nearest-even
    return (ushort_t)(r >> 16);
}

// ============ prep: zero mask || x -> bf16 row-major || W -> W^T bf16 ============
__global__ __launch_bounds__(256) void prep_kernel(const float* __restrict__ x,
                                                   const float* __restrict__ W,
                                                   unsigned int* __restrict__ mask,
                                                   ushort_t* __restrict__ xb,
                                                   ushort_t* __restrict__ wt) {
    int b = blockIdx.x, t = threadIdx.x;
    if (b < ZB) {
        *reinterpret_cast<uint4*>(mask + (size_t)(b * 256 + t) * 4) = make_uint4(0u, 0u, 0u, 0u);
    } else if (b < ZB + XB) {
        int i = (b - ZB) * 256 + t;           // float4 index, 262144 total
        float4 v = *reinterpret_cast<const float4*>(x + (size_t)i * 4);
        ushort4 o;
        o.x = f32_to_bf16(v.x); o.y = f32_to_bf16(v.y);
        o.z = f32_to_bf16(v.z); o.w = f32_to_bf16(v.w);
        *reinterpret_cast<ushort4*>(xb + (size_t)i * 4) = o;
    } else {
        int e = (b - ZB - XB) * 256 + t;      // 131072 = 256x512 elems of W
        int k = e >> 9, n = e & 511;
        wt[(size_t)n * INF_ + k] = f32_to_bf16(W[e]);
    }
}

// ============ MFMA GEMM h = x@W (+ es/ed epilogue)  ||  adjacency scatter ============
// gemm blocks: bi=b>>3 (64-row tile), bj=b&7 (head / 64-col tile)
// wave w: rows w*16..+15 of tile; col-tiles c=0..3
__global__ __launch_bounds__(256) void gemm_adj(const ushort_t* __restrict__ xb,
                                                const ushort_t* __restrict__ wt,
                                                const float* __restrict__ a,
                                                const int* __restrict__ ei,
                                                unsigned int* __restrict__ mask,
                                                ushort_t* __restrict__ hout,
                                                float* __restrict__ es,
                                                float* __restrict__ ed) {
    int b = blockIdx.x, t = threadIdx.x;

    if (b >= GEMM_BLOCKS) {
        // ---- adjacency path (bitmask OR dedups duplicate edges) ----
        int e = (b - GEMM_BLOCKS) * 256 + t;
        if (e < NEDGES) {
            int src = ei[e];
            int dst = ei[NEDGES + e];
            atomicOr(&mask[src * MWORDS + (dst >> 5)], 1u << (dst & 31));
        }
        if (e < NNODES) {  // self loop (adj + eye)
            atomicOr(&mask[e * MWORDS + (e >> 5)], 1u << (e & 31));
        }
        return;
    }

    int bi = b >> 3, bj = b & 7;
    int w  = t >> 6, l = t & 63;
    int lr = l & 15, lk = l >> 4;   // A-frag: row=lr, k=lk*8+j ; B-frag: col=lr, k=lk*8+j

    const ushort_t* ap = xb + (size_t)(bi * 64 + w * 16 + lr) * INF_ + lk * 8;
    const ushort_t* bp = wt + (size_t)(bj * 64 + lr) * INF_ + lk * 8;

    f32x4 acc[4];
    #pragma unroll
    for (int c = 0; c < 4; ++c) acc[c] = (f32x4){0.f, 0.f, 0.f, 0.f};

    #pragma unroll
    for (int k0 = 0; k0 < INF_; k0 += 32) {
        U16x8 af;
        af.u = *reinterpret_cast<const uint4*>(ap + k0);
        #pragma unroll
        for (int c = 0; c < 4; ++c) {
            U16x8 bf_;
            bf_.u = *reinterpret_cast<const uint4*>(bp + (size_t)c * 16 * INF_ + k0);
            acc[c] = __builtin_amdgcn_mfma_f32_16x16x32_bf16(af.v, bf_.v, acc[c], 0, 0, 0);
        }
    }

    // ---- epilogue: h store (bf16) ----  C/D: col=lane&15, row=(lane>>4)*4+reg
    int growbase = bi * 64 + w * 16 + lk * 4;
    #pragma unroll
    for (int c = 0; c < 4; ++c) {
        int gcol = bj * 64 + c * 16 + lr;
        #pragma unroll
        for (int r = 0; r < 4; ++r)
            hout[(size_t)(growbase + r) * HO + gcol] = f32_to_bf16(acc[c][r]);
    }

    // ---- epilogue: es/ed (per-row dot with a_src/a_dst over this head's 64 cols) ----
    float ps[4] = {0.f, 0.f, 0.f, 0.f}, pd[4] = {0.f, 0.f, 0.f, 0.f};
    #pragma unroll
    for (int c = 0; c < 4; ++c) {
        int col64 = c * 16 + lr;
        float as_ = a[bj * 2 * FDIM + col64];
        float ad_ = a[bj * 2 * FDIM + FDIM + col64];
        #pragma unroll
        for (int r = 0; r < 4; ++r) {
            ps[r] += acc[c][r] * as_;
            pd[r] += acc[c][r] * ad_;
        }
    }
    #pragma unroll
    for (int r = 0; r < 4; ++r) {
        #pragma unroll
        for (int off = 1; off < 16; off <<= 1) {
            ps[r] += __shfl_xor(ps[r], off, 16);
            pd[r] += __shfl_xor(pd[r], off, 16);
        }
        if (lr == 0) {
            int grow = growbase + r;
            es[grow * HEADS + bj] = ps[r];
            ed[grow * HEADS + bj] = pd[r];
        }
    }
}

// ============ per-row softmax + aggregation, one block per destination row ============
__global__ __launch_bounds__(256) void gat_aggregate(const ushort_t* __restrict__ h,
                                                     const float* __restrict__ es,
                                                     const float* __restrict__ ed,
                                                     const unsigned int* __restrict__ mask,
                                                     float* __restrict__ out) {
    int i = blockIdx.x;
    int t = threadIdx.x;
    int wave = t >> 6, lane = t & 63;
    __shared__ unsigned short list[NNODES];   // 8 KB (max degree)
    __shared__ float red[4][HO];              // 8 KB per-wave feature partials
    __shared__ float redd[4][HEADS];
    __shared__ int   s_w0, s_deg;

    // ---- deterministic list build: popcount + wave prefix scan ----
    unsigned int bits = 0;
    int cnt = 0, incl = 0;
    if (t < 128) {
        bits = mask[(size_t)i * MWORDS + t];
        cnt = __popc(bits);
        incl = cnt;
        #pragma unroll
        for (int off = 1; off < 64; off <<= 1) {
            int v = __shfl_up(incl, off);
            if (lane >= off) incl += v;
        }
    }
    if (t == 63) s_w0 = incl;
    __syncthreads();
    if (t >= 64 && t < 128) incl += s_w0;
    if (t == 127) s_deg = incl;
    if (t < 128) {
        int pos = incl - cnt;
        int base = t * 32;
        while (bits) {
            int bbit = __ffs(bits) - 1;
            bits &= bits - 1;
            list[pos++] = (unsigned short)(base + bbit);
        }
    }
    __syncthreads();
    int deg = s_deg;

    // ---- accumulate: wave w takes neighbors w, w+4, ...; lane owns features lane*8..+7 ----
    int hh = lane >> 3;
    int f0 = lane * 8;
    float es_h = es[i * HEADS + hh];
    float acc[8] = {0.f, 0.f, 0.f, 0.f, 0.f, 0.f, 0.f, 0.f};
    float den = 0.f;
    for (int jj = wave; jj < deg; jj += 4) {
        int j = list[jj];
        float s = es_h + ed[j * HEADS + hh];
        s = s > 0.f ? s : NEG_SLOPE * s;
        float w = __expf(s);
        uint4 v = *reinterpret_cast<const uint4*>(h + (size_t)j * HO + f0);  // 8 bf16
        acc[0] += w * bf16_to_f32((ushort_t)(v.x & 0xFFFF));
        acc[1] += w * bf16_to_f32((ushort_t)(v.x >> 16));
        acc[2] += w * bf16_to_f32((ushort_t)(v.y & 0xFFFF));
        acc[3] += w * bf16_to_f32((ushort_t)(v.y >> 16));
        acc[4] += w * bf16_to_f32((ushort_t)(v.z & 0xFFFF));
        acc[5] += w * bf16_to_f32((ushort_t)(v.z >> 16));
        acc[6] += w * bf16_to_f32((ushort_t)(v.w & 0xFFFF));
        acc[7] += w * bf16_to_f32((ushort_t)(v.w >> 16));
        den += w;
    }
    float4 a0 = {acc[0], acc[1], acc[2], acc[3]};
    float4 a1 = {acc[4], acc[5], acc[6], acc[7]};
    *reinterpret_cast<float4*>(&red[wave][f0]) = a0;
    *reinterpret_cast<float4*>(&red[wave][f0 + 4]) = a1;
    if ((lane & 7) == 0) redd[wave][hh] = den;
    __syncthreads();

    #pragma unroll
    for (int ff = t; ff < HO; ff += 256) {
        float sum = red[0][ff] + red[1][ff] + red[2][ff] + red[3][ff];
        int hd = ff >> 6;
        float d = redd[0][hd] + redd[1][hd] + redd[2][hd] + redd[3][hd];
        out[(size_t)i * HO + ff] = sum / d;
    }
}

extern "C" void kernel_launch(void* const* d_in, const int* in_sizes, int n_in,
                              void* d_out, int out_size, void* d_ws, size_t ws_size,
                              hipStream_t stream) {
    const float* x  = (const float*)d_in[0];
    const int*   ei = (const int*)d_in[1];
    const float* W  = (const float*)d_in[2];
    const float* a  = (const float*)d_in[3];
    float* out = (float*)d_out;

    char* ws = (char*)d_ws;
    ushort_t* h  = (ushort_t*)ws;                               // 4 MB
    float* es = (float*)(ws + (size_t)NNODES * HO * 2);         // 128 KB
    float* ed = es + NNODES * HEADS;                            // 128 KB
    unsigned int* mask = (unsigned int*)(ed + NNODES * HEADS);  // 2 MB
    ushort_t* xb = (ushort_t*)(mask + (size_t)NNODES * MWORDS); // 2 MB
    ushort_t* wt = xb + (size_t)NNODES * INF_;                  // 256 KB

    hipLaunchKernelGGL(prep_kernel, dim3(ZB + XB + WB), dim3(256), 0, stream,
                       x, W, mask, xb, wt);
    hipLaunchKernelGGL(gemm_adj, dim3(GEMM_BLOCKS + ADJ_BLOCKS), dim3(256), 0, stream,
                       xb, wt, a, ei, mask, h, es, ed);
    hipLaunchKernelGGL(gat_aggregate, dim3(NNODES), dim3(256), 0, stream, h, es, ed, mask, out);
}

// Round 6
// 37.963 us; speedup vs baseline: 1.9576x; 1.0676x over previous
//
#include <hip/hip_runtime.h>

#define NNODES 4096
#define INF_   256
#define HEADS  8
#define FDIM   64
#define HO     512            // HEADS*FDIM
#define NEDGES 131072
#define NEG_SLOPE 0.2f
#define MWORDS 128            // 4096 bits / 32 per row

#define ZB 512                // prep: zero-mask blocks
#define XB 1024               // prep: x-convert blocks
#define WB 512                // prep: W-transpose blocks
#define GEMM_BLOCKS 512       // 64 row-tiles x 8 col-tiles(heads)
#define ADJ_BLOCKS  512       // 131072 / 256
#define LCAP 1092             // per-row neighbor list capacity (max deg here ~70)

typedef unsigned short ushort_t;
typedef short bf16x8 __attribute__((ext_vector_type(8)));
typedef float f32x4  __attribute__((ext_vector_type(4)));

union U16x8 { uint4 u; bf16x8 v; };

__device__ __forceinline__ float bf16_to_f32(ushort_t u) {
    union { unsigned int i; float f; } c;
    c.i = ((unsigned int)u) << 16;
    return c.f;
}
__device__ __forceinline__ ushort_t f32_to_bf16(float f) {
    union { float f; unsigned int i; } c;
    c.f = f;
    unsigned int r = c.i + 0x7FFF + ((c.i >> 16) & 1);  // RNE
    return (ushort_t)(r >> 16);
}

// ============ prep: zero mask || x -> bf16 row-major || W -> W^T bf16 ============
__global__ __launch_bounds__(256) void prep_kernel(const float* __restrict__ x,
                                                   const float* __restrict__ W,
                                                   unsigned int* __restrict__ mask,
                                                   ushort_t* __restrict__ xb,
                                                   ushort_t* __restrict__ wt) {
    int b = blockIdx.x, t = threadIdx.x;
    if (b < ZB) {
        *reinterpret_cast<uint4*>(mask + (size_t)(b * 256 + t) * 4) = make_uint4(0u, 0u, 0u, 0u);
    } else if (b < ZB + XB) {
        int i = (b - ZB) * 256 + t;
        float4 v = *reinterpret_cast<const float4*>(x + (size_t)i * 4);
        ushort4 o;
        o.x = f32_to_bf16(v.x); o.y = f32_to_bf16(v.y);
        o.z = f32_to_bf16(v.z); o.w = f32_to_bf16(v.w);
        *reinterpret_cast<ushort4*>(xb + (size_t)i * 4) = o;
    } else {
        int e = (b - ZB - XB) * 256 + t;      // 131072 = 256x512 elems of W
        int k = e >> 9, n = e & 511;
        wt[(size_t)n * INF_ + k] = f32_to_bf16(W[e]);
    }
}

// ============ MFMA GEMM h = x@W (+ es/ed epilogue)  ||  adjacency scatter ============
__global__ __launch_bounds__(256) void gemm_adj(const ushort_t* __restrict__ xb,
                                                const ushort_t* __restrict__ wt,
                                                const float* __restrict__ a,
                                                const int* __restrict__ ei,
                                                unsigned int* __restrict__ mask,
                                                ushort_t* __restrict__ hout,
                                                float* __restrict__ es,
                                                float* __restrict__ ed) {
    int b = blockIdx.x, t = threadIdx.x;

    if (b >= GEMM_BLOCKS) {
        int e = (b - GEMM_BLOCKS) * 256 + t;
        if (e < NEDGES) {
            int src = ei[e];
            int dst = ei[NEDGES + e];
            atomicOr(&mask[src * MWORDS + (dst >> 5)], 1u << (dst & 31));
        }
        if (e < NNODES) {
            atomicOr(&mask[e * MWORDS + (e >> 5)], 1u << (e & 31));
        }
        return;
    }

    int bi = b >> 3, bj = b & 7;
    int w  = t >> 6, l = t & 63;
    int lr = l & 15, lk = l >> 4;

    const ushort_t* ap = xb + (size_t)(bi * 64 + w * 16 + lr) * INF_ + lk * 8;
    const ushort_t* bp = wt + (size_t)(bj * 64 + lr) * INF_ + lk * 8;

    f32x4 acc[4];
    #pragma unroll
    for (int c = 0; c < 4; ++c) acc[c] = (f32x4){0.f, 0.f, 0.f, 0.f};

    #pragma unroll
    for (int k0 = 0; k0 < INF_; k0 += 32) {
        U16x8 af;
        af.u = *reinterpret_cast<const uint4*>(ap + k0);
        #pragma unroll
        for (int c = 0; c < 4; ++c) {
            U16x8 bf_;
            bf_.u = *reinterpret_cast<const uint4*>(bp + (size_t)c * 16 * INF_ + k0);
            acc[c] = __builtin_amdgcn_mfma_f32_16x16x32_bf16(af.v, bf_.v, acc[c], 0, 0, 0);
        }
    }

    // C/D: col=lane&15, row=(lane>>4)*4+reg
    int growbase = bi * 64 + w * 16 + lk * 4;
    #pragma unroll
    for (int c = 0; c < 4; ++c) {
        int gcol = bj * 64 + c * 16 + lr;
        #pragma unroll
        for (int r = 0; r < 4; ++r)
            hout[(size_t)(growbase + r) * HO + gcol] = f32_to_bf16(acc[c][r]);
    }

    float ps[4] = {0.f, 0.f, 0.f, 0.f}, pd[4] = {0.f, 0.f, 0.f, 0.f};
    #pragma unroll
    for (int c = 0; c < 4; ++c) {
        int col64 = c * 16 + lr;
        float as_ = a[bj * 2 * FDIM + col64];
        float ad_ = a[bj * 2 * FDIM + FDIM + col64];
        #pragma unroll
        for (int r = 0; r < 4; ++r) {
            ps[r] += acc[c][r] * as_;
            pd[r] += acc[c][r] * ad_;
        }
    }
    #pragma unroll
    for (int r = 0; r < 4; ++r) {
        #pragma unroll
        for (int off = 1; off < 16; off <<= 1) {
            ps[r] += __shfl_xor(ps[r], off, 16);
            pd[r] += __shfl_xor(pd[r], off, 16);
        }
        if (lr == 0) {
            int grow = growbase + r;
            es[grow * HEADS + bj] = ps[r];
            ed[grow * HEADS + bj] = pd[r];
        }
    }
}

// ============ aggregation: ONE WAVE per destination row ============
// Every lane iterates ALL neighbors for its own 8 features -> denominator is
// lane-local, no cross-wave reduction. 2 neighbors/iter for MLP.
__global__ __launch_bounds__(256) void gat_aggregate(const ushort_t* __restrict__ h,
                                                     const float* __restrict__ es,
                                                     const float* __restrict__ ed,
                                                     const unsigned int* __restrict__ mask,
                                                     float* __restrict__ out) {
    int w = threadIdx.x >> 6, lane = threadIdx.x & 63;
    int i = blockIdx.x * 4 + w;
    __shared__ unsigned short list_s[4][LCAP];
    unsigned short* mylist = list_s[w];

    // ---- per-wave deterministic list build (popcount + 64-lane scans) ----
    const unsigned int* row = mask + (size_t)i * MWORDS;
    unsigned int b0 = row[lane], b1 = row[64 + lane];
    int c0 = __popc(b0), c1 = __popc(b1);
    int s0 = c0;
    #pragma unroll
    for (int off = 1; off < 64; off <<= 1) { int v = __shfl_up(s0, off); if (lane >= off) s0 += v; }
    int tot0 = __shfl(s0, 63);
    int s1 = c1;
    #pragma unroll
    for (int off = 1; off < 64; off <<= 1) { int v = __shfl_up(s1, off); if (lane >= off) s1 += v; }
    int deg = tot0 + __shfl(s1, 63);
    int p0 = s0 - c0;
    int p1 = tot0 + s1 - c1;
    int base0 = lane * 32, base1 = (64 + lane) * 32;
    while (b0) {
        int bit = __ffs(b0) - 1; b0 &= b0 - 1;
        if (p0 < LCAP) mylist[p0] = (unsigned short)(base0 + bit);
        ++p0;
    }
    while (b1) {
        int bit = __ffs(b1) - 1; b1 &= b1 - 1;
        if (p1 < LCAP) mylist[p1] = (unsigned short)(base1 + bit);
        ++p1;
    }
    __syncthreads();   // cheap; guarantees cross-lane LDS visibility

    // ---- main loop: all lanes over all neighbors, 2 per iteration ----
    int hh = lane >> 3;
    int f0 = lane * 8;
    float es_h = es[i * HEADS + hh];
    float acc[8] = {0.f, 0.f, 0.f, 0.f, 0.f, 0.f, 0.f, 0.f};
    float den = 0.f;
    int jj = 0;
    for (; jj + 2 <= deg; jj += 2) {
        int ja = mylist[jj], jb = mylist[jj + 1];
        float ea = ed[ja * HEADS + hh];
        float eb = ed[jb * HEADS + hh];
        uint4 va = *reinterpret_cast<const uint4*>(h + (size_t)ja * HO + f0);
        uint4 vb = *reinterpret_cast<const uint4*>(h + (size_t)jb * HO + f0);
        float sa = es_h + ea; sa = sa > 0.f ? sa : NEG_SLOPE * sa;
        float sb = es_h + eb; sb = sb > 0.f ? sb : NEG_SLOPE * sb;
        float wa = __expf(sa), wb = __expf(sb);
        den += wa + wb;
        acc[0] += wa * bf16_to_f32((ushort_t)(va.x & 0xFFFF)) + wb * bf16_to_f32((ushort_t)(vb.x & 0xFFFF));
        acc[1] += wa * bf16_to_f32((ushort_t)(va.x >> 16))    + wb * bf16_to_f32((ushort_t)(vb.x >> 16));
        acc[2] += wa * bf16_to_f32((ushort_t)(va.y & 0xFFFF)) + wb * bf16_to_f32((ushort_t)(vb.y & 0xFFFF));
        acc[3] += wa * bf16_to_f32((ushort_t)(va.y >> 16))    + wb * bf16_to_f32((ushort_t)(vb.y >> 16));
        acc[4] += wa * bf16_to_f32((ushort_t)(va.z & 0xFFFF)) + wb * bf16_to_f32((ushort_t)(vb.z & 0xFFFF));
        acc[5] += wa * bf16_to_f32((ushort_t)(va.z >> 16))    + wb * bf16_to_f32((ushort_t)(vb.z >> 16));
        acc[6] += wa * bf16_to_f32((ushort_t)(va.w & 0xFFFF)) + wb * bf16_to_f32((ushort_t)(vb.w & 0xFFFF));
        acc[7] += wa * bf16_to_f32((ushort_t)(va.w >> 16))    + wb * bf16_to_f32((ushort_t)(vb.w >> 16));
    }
    if (jj < deg) {
        int ja = mylist[jj];
        float ea = ed[ja * HEADS + hh];
        uint4 va = *reinterpret_cast<const uint4*>(h + (size_t)ja * HO + f0);
        float sa = es_h + ea; sa = sa > 0.f ? sa : NEG_SLOPE * sa;
        float wa = __expf(sa);
        den += wa;
        acc[0] += wa * bf16_to_f32((ushort_t)(va.x & 0xFFFF));
        acc[1] += wa * bf16_to_f32((ushort_t)(va.x >> 16));
        acc[2] += wa * bf16_to_f32((ushort_t)(va.y & 0xFFFF));
        acc[3] += wa * bf16_to_f32((ushort_t)(va.y >> 16));
        acc[4] += wa * bf16_to_f32((ushort_t)(va.z & 0xFFFF));
        acc[5] += wa * bf16_to_f32((ushort_t)(va.z >> 16));
        acc[6] += wa * bf16_to_f32((ushort_t)(va.w & 0xFFFF));
        acc[7] += wa * bf16_to_f32((ushort_t)(va.w >> 16));
    }

    float inv = 1.0f / den;
    float4 o0 = {acc[0] * inv, acc[1] * inv, acc[2] * inv, acc[3] * inv};
    float4 o1 = {acc[4] * inv, acc[5] * inv, acc[6] * inv, acc[7] * inv};
    float* op = out + (size_t)i * HO + f0;
    *reinterpret_cast<float4*>(op) = o0;
    *reinterpret_cast<float4*>(op + 4) = o1;
}

extern "C" void kernel_launch(void* const* d_in, const int* in_sizes, int n_in,
                              void* d_out, int out_size, void* d_ws, size_t ws_size,
                              hipStream_t stream) {
    const float* x  = (const float*)d_in[0];
    const int*   ei = (const int*)d_in[1];
    const float* W  = (const float*)d_in[2];
    const float* a  = (const float*)d_in[3];
    float* out = (float*)d_out;

    char* ws = (char*)d_ws;
    ushort_t* h  = (ushort_t*)ws;                               // 4 MB
    float* es = (float*)(ws + (size_t)NNODES * HO * 2);         // 128 KB
    float* ed = es + NNODES * HEADS;                            // 128 KB
    unsigned int* mask = (unsigned int*)(ed + NNODES * HEADS);  // 2 MB
    ushort_t* xb = (ushort_t*)(mask + (size_t)NNODES * MWORDS); // 2 MB
    ushort_t* wt = xb + (size_t)NNODES * INF_;                  // 256 KB

    hipLaunchKernelGGL(prep_kernel, dim3(ZB + XB + WB), dim3(256), 0, stream,
                       x, W, mask, xb, wt);
    hipLaunchKernelGGL(gemm_adj, dim3(GEMM_BLOCKS + ADJ_BLOCKS), dim3(256), 0, stream,
                       xb, wt, a, ei, mask, h, es, ed);
    hipLaunchKernelGGL(gat_aggregate, dim3(NNODES / 4), dim3(256), 0, stream, h, es, ed, mask, out);
}

// Round 8
// 37.354 us; speedup vs baseline: 1.9896x; 1.0163x over previous
//
#include <hip/hip_runtime.h>

#define NNODES 4096
#define INF_   256
#define HEADS  8
#define FDIM   64
#define HO     512            // HEADS*FDIM
#define NEDGES 131072
#define NEG_SLOPE 0.2f
#define MWORDS 128            // 4096 bits / 32 per row

#define ZB 512                // prep: zero-mask blocks
#define XB 1024               // prep: x-convert blocks
#define WTB 32                // prep: W-transpose tiles (4 k-tiles x 8 n-tiles of 64x64)
#define GEMM_BLOCKS 512       // 64 row-tiles x 8 col-tiles(heads)
#define ADJ_BLOCKS  512       // 131072 / 256
#define LCAP 1092             // per-row neighbor list capacity (max deg here ~70)

typedef unsigned short ushort_t;
typedef short bf16x8 __attribute__((ext_vector_type(8)));
typedef float f32x4  __attribute__((ext_vector_type(4)));

union U16x8 { uint4 u; bf16x8 v; };

__device__ __forceinline__ float bf16_to_f32(ushort_t u) {
    union { unsigned int i; float f; } c;
    c.i = ((unsigned int)u) << 16;
    return c.f;
}
__device__ __forceinline__ ushort_t f32_to_bf16(float f) {
    union { float f; unsigned int i; } c;
    c.f = f;
    unsigned int r = c.i + 0x7FFF + ((c.i >> 16) & 1);  // RNE
    return (ushort_t)(r >> 16);
}

// ============ prep: zero mask || x -> bf16 row-major || W -> W^T bf16 (LDS-tiled) ============
__global__ __launch_bounds__(256) void prep_kernel(const float* __restrict__ x,
                                                   const float* __restrict__ W,
                                                   unsigned int* __restrict__ mask,
                                                   ushort_t* __restrict__ xb,
                                                   ushort_t* __restrict__ wt) {
    __shared__ float tile[64][65];
    int b = blockIdx.x, t = threadIdx.x;
    if (b < ZB) {
        *reinterpret_cast<uint4*>(mask + (size_t)(b * 256 + t) * 4) = make_uint4(0u, 0u, 0u, 0u);
    } else if (b < ZB + XB) {
        int i = (b - ZB) * 256 + t;
        float4 v = *reinterpret_cast<const float4*>(x + (size_t)i * 4);
        ushort4 o;
        o.x = f32_to_bf16(v.x); o.y = f32_to_bf16(v.y);
        o.z = f32_to_bf16(v.z); o.w = f32_to_bf16(v.w);
        *reinterpret_cast<ushort4*>(xb + (size_t)i * 4) = o;
    } else {
        // ---- W^T tile: W[k0..k0+63][n0..n0+63] -> wt[n][k], coalesced both sides ----
        int wb = b - ZB - XB;          // 0..31
        int k0 = (wb >> 3) * 64;       // 4 k-tiles
        int n0 = (wb & 7) * 64;        // 8 n-tiles
        int row = t >> 2, c4 = t & 3;  // read: row 0..63, 4 float4-cols per thread
        #pragma unroll
        for (int it = 0; it < 4; ++it) {
            int f4 = c4 + it * 4;      // 0..15
            float4 v = *reinterpret_cast<const float4*>(&W[(size_t)(k0 + row) * HO + n0 + f4 * 4]);
            tile[row][f4 * 4 + 0] = v.x;
            tile[row][f4 * 4 + 1] = v.y;
            tile[row][f4 * 4 + 2] = v.z;
            tile[row][f4 * 4 + 3] = v.w;
        }
        __syncthreads();
        int n = t >> 2;                // write: n row 0..63, 4 ushort4-chunks per thread
        #pragma unroll
        for (int it = 0; it < 4; ++it) {
            int ch = (t & 3) + it * 4; // 0..15 -> k-chunk of 4
            ushort4 o;
            o.x = f32_to_bf16(tile[ch * 4 + 0][n]);
            o.y = f32_to_bf16(tile[ch * 4 + 1][n]);
            o.z = f32_to_bf16(tile[ch * 4 + 2][n]);
            o.w = f32_to_bf16(tile[ch * 4 + 3][n]);
            *reinterpret_cast<ushort4*>(&wt[(size_t)(n0 + n) * INF_ + k0 + ch * 4]) = o;
        }
    }
}

// ============ MFMA GEMM h = x@W (+ es/ed epilogue)  ||  adjacency scatter ============
__global__ __launch_bounds__(256) void gemm_adj(const ushort_t* __restrict__ xb,
                                                const ushort_t* __restrict__ wt,
                                                const float* __restrict__ a,
                                                const int* __restrict__ ei,
                                                unsigned int* __restrict__ mask,
                                                ushort_t* __restrict__ hout,
                                                float* __restrict__ es,
                                                float* __restrict__ ed) {
    int b = blockIdx.x, t = threadIdx.x;

    if (b >= GEMM_BLOCKS) {
        int e = (b - GEMM_BLOCKS) * 256 + t;
        if (e < NEDGES) {
            int src = ei[e];
            int dst = ei[NEDGES + e];
            atomicOr(&mask[src * MWORDS + (dst >> 5)], 1u << (dst & 31));
        }
        if (e < NNODES) {
            atomicOr(&mask[e * MWORDS + (e >> 5)], 1u << (e & 31));
        }
        return;
    }

    int bi = b >> 3, bj = b & 7;
    int w  = t >> 6, l = t & 63;
    int lr = l & 15, lk = l >> 4;

    const ushort_t* ap = xb + (size_t)(bi * 64 + w * 16 + lr) * INF_ + lk * 8;
    const ushort_t* bp = wt + (size_t)(bj * 64 + lr) * INF_ + lk * 8;

    f32x4 acc[4];
    #pragma unroll
    for (int c = 0; c < 4; ++c) acc[c] = (f32x4){0.f, 0.f, 0.f, 0.f};

    #pragma unroll
    for (int k0 = 0; k0 < INF_; k0 += 32) {
        U16x8 af;
        af.u = *reinterpret_cast<const uint4*>(ap + k0);
        #pragma unroll
        for (int c = 0; c < 4; ++c) {
            U16x8 bf_;
            bf_.u = *reinterpret_cast<const uint4*>(bp + (size_t)c * 16 * INF_ + k0);
            acc[c] = __builtin_amdgcn_mfma_f32_16x16x32_bf16(af.v, bf_.v, acc[c], 0, 0, 0);
        }
    }

    // C/D: col=lane&15, row=(lane>>4)*4+reg
    int growbase = bi * 64 + w * 16 + lk * 4;
    #pragma unroll
    for (int c = 0; c < 4; ++c) {
        int gcol = bj * 64 + c * 16 + lr;
        #pragma unroll
        for (int r = 0; r < 4; ++r)
            hout[(size_t)(growbase + r) * HO + gcol] = f32_to_bf16(acc[c][r]);
    }

    float ps[4] = {0.f, 0.f, 0.f, 0.f}, pd[4] = {0.f, 0.f, 0.f, 0.f};
    #pragma unroll
    for (int c = 0; c < 4; ++c) {
        int col64 = c * 16 + lr;
        float as_ = a[bj * 2 * FDIM + col64];
        float ad_ = a[bj * 2 * FDIM + FDIM + col64];
        #pragma unroll
        for (int r = 0; r < 4; ++r) {
            ps[r] += acc[c][r] * as_;
            pd[r] += acc[c][r] * ad_;
        }
    }
    #pragma unroll
    for (int r = 0; r < 4; ++r) {
        #pragma unroll
        for (int off = 1; off < 16; off <<= 1) {
            ps[r] += __shfl_xor(ps[r], off, 16);
            pd[r] += __shfl_xor(pd[r], off, 16);
        }
        if (lr == 0) {
            int grow = growbase + r;
            es[grow * HEADS + bj] = ps[r];
            ed[grow * HEADS + bj] = pd[r];
        }
    }
}

// ============ aggregation: ONE WAVE per destination row, 4 neighbors in flight ============
__device__ __forceinline__ void agg_one(float wgt, uint4 v, float* acc) {
    acc[0] += wgt * bf16_to_f32((ushort_t)(v.x & 0xFFFF));
    acc[1] += wgt * bf16_to_f32((ushort_t)(v.x >> 16));
    acc[2] += wgt * bf16_to_f32((ushort_t)(v.y & 0xFFFF));
    acc[3] += wgt * bf16_to_f32((ushort_t)(v.y >> 16));
    acc[4] += wgt * bf16_to_f32((ushort_t)(v.z & 0xFFFF));
    acc[5] += wgt * bf16_to_f32((ushort_t)(v.z >> 16));
    acc[6] += wgt * bf16_to_f32((ushort_t)(v.w & 0xFFFF));
    acc[7] += wgt * bf16_to_f32((ushort_t)(v.w >> 16));
}

__global__ __launch_bounds__(256) void gat_aggregate(const ushort_t* __restrict__ h,
                                                     const float* __restrict__ es,
                                                     const float* __restrict__ ed,
                                                     const unsigned int* __restrict__ mask,
                                                     float* __restrict__ out) {
    int w = threadIdx.x >> 6, lane = threadIdx.x & 63;
    int i = blockIdx.x * 4 + w;
    __shared__ unsigned short list_s[4][LCAP];
    unsigned short* mylist = list_s[w];

    // ---- per-wave deterministic list build (popcount + 64-lane scans) ----
    const unsigned int* row = mask + (size_t)i * MWORDS;
    unsigned int b0 = row[lane], b1 = row[64 + lane];
    int c0 = __popc(b0), c1 = __popc(b1);
    int s0 = c0;
    #pragma unroll
    for (int off = 1; off < 64; off <<= 1) { int v = __shfl_up(s0, off); if (lane >= off) s0 += v; }
    int tot0 = __shfl(s0, 63);
    int s1 = c1;
    #pragma unroll
    for (int off = 1; off < 64; off <<= 1) { int v = __shfl_up(s1, off); if (lane >= off) s1 += v; }
    int deg = tot0 + __shfl(s1, 63);
    int p0 = s0 - c0;
    int p1 = tot0 + s1 - c1;
    int base0 = lane * 32, base1 = (64 + lane) * 32;
    while (b0) {
        int bit = __ffs(b0) - 1; b0 &= b0 - 1;
        if (p0 < LCAP) mylist[p0] = (unsigned short)(base0 + bit);
        ++p0;
    }
    while (b1) {
        int bit = __ffs(b1) - 1; b1 &= b1 - 1;
        if (p1 < LCAP) mylist[p1] = (unsigned short)(base1 + bit);
        ++p1;
    }
    __syncthreads();

    // ---- main loop: all lanes over all neighbors, 4 per iteration ----
    int hh = lane >> 3;
    int f0 = lane * 8;
    float es_h = es[i * HEADS + hh];
    float acc[8] = {0.f, 0.f, 0.f, 0.f, 0.f, 0.f, 0.f, 0.f};
    float den = 0.f;
    int jj = 0;
    for (; jj + 4 <= deg; jj += 4) {
        int ja = mylist[jj], jb = mylist[jj + 1], jc = mylist[jj + 2], jd = mylist[jj + 3];
        float ea = ed[ja * HEADS + hh];
        float eb = ed[jb * HEADS + hh];
        float ec = ed[jc * HEADS + hh];
        float ee = ed[jd * HEADS + hh];
        uint4 va = *reinterpret_cast<const uint4*>(h + (size_t)ja * HO + f0);
        uint4 vb = *reinterpret_cast<const uint4*>(h + (size_t)jb * HO + f0);
        uint4 vc = *reinterpret_cast<const uint4*>(h + (size_t)jc * HO + f0);
        uint4 vd = *reinterpret_cast<const uint4*>(h + (size_t)jd * HO + f0);
        float sa = es_h + ea; sa = sa > 0.f ? sa : NEG_SLOPE * sa;
        float sb = es_h + eb; sb = sb > 0.f ? sb : NEG_SLOPE * sb;
        float sc = es_h + ec; sc = sc > 0.f ? sc : NEG_SLOPE * sc;
        float sd = es_h + ee; sd = sd > 0.f ? sd : NEG_SLOPE * sd;
        float wa = __expf(sa), wb = __expf(sb), wc = __expf(sc), wd = __expf(sd);
        den += (wa + wb) + (wc + wd);
        agg_one(wa, va, acc);
        agg_one(wb, vb, acc);
        agg_one(wc, vc, acc);
        agg_one(wd, vd, acc);
    }
    for (; jj < deg; ++jj) {
        int ja = mylist[jj];
        float ea = ed[ja * HEADS + hh];
        uint4 va = *reinterpret_cast<const uint4*>(h + (size_t)ja * HO + f0);
        float sa = es_h + ea; sa = sa > 0.f ? sa : NEG_SLOPE * sa;
        float wa = __expf(sa);
        den += wa;
        agg_one(wa, va, acc);
    }

    float inv = 1.0f / den;
    f32x4 o0 = {acc[0] * inv, acc[1] * inv, acc[2] * inv, acc[3] * inv};
    f32x4 o1 = {acc[4] * inv, acc[5] * inv, acc[6] * inv, acc[7] * inv};
    float* op = out + (size_t)i * HO + f0;
    __builtin_nontemporal_store(o0, reinterpret_cast<f32x4*>(op));
    __builtin_nontemporal_store(o1, reinterpret_cast<f32x4*>(op + 4));
}

extern "C" void kernel_launch(void* const* d_in, const int* in_sizes, int n_in,
                              void* d_out, int out_size, void* d_ws, size_t ws_size,
                              hipStream_t stream) {
    const float* x  = (const float*)d_in[0];
    const int*   ei = (const int*)d_in[1];
    const float* W  = (const float*)d_in[2];
    const float* a  = (const float*)d_in[3];
    float* out = (float*)d_out;

    char* ws = (char*)d_ws;
    ushort_t* h  = (ushort_t*)ws;                               // 4 MB
    float* es = (float*)(ws + (size_t)NNODES * HO * 2);         // 128 KB
    float* ed = es + NNODES * HEADS;                            // 128 KB
    unsigned int* mask = (unsigned int*)(ed + NNODES * HEADS);  // 2 MB
    ushort_t* xb = (ushort_t*)(mask + (size_t)NNODES * MWORDS); // 2 MB
    ushort_t* wt = xb + (size_t)NNODES * INF_;                  // 256 KB

    hipLaunchKernelGGL(prep_kernel, dim3(ZB + XB + WTB), dim3(256), 0, stream,
                       x, W, mask, xb, wt);
    hipLaunchKernelGGL(gemm_adj, dim3(GEMM_BLOCKS + ADJ_BLOCKS), dim3(256), 0, stream,
                       xb, wt, a, ei, mask, h, es, ed);
    hipLaunchKernelGGL(gat_aggregate, dim3(NNODES / 4), dim3(256), 0, stream, h, es, ed, mask, out);
}